// Round 13
// baseline (276.438 us; speedup 1.0000x reference)
//
#include <hip/hip_runtime.h>
#include <math.h>

// ---------------- geometry constants ----------------
#define NXg      192
#define PLANE_SZ (NXg*NXg)            // 36864
#define PLANES   16                   // B(2) * NR(8)
#define TOTAL    (PLANES*PLANE_SZ)
#define NT       200
#define NM       32
#define CW       96                   // central window width
#define WIN0     48                   // central window origin
#define W96SQ    (CW*CW)
#define A0       24                   // active domain [24,168)^2
#define TILE     36                   // interior tile, 16 tiles/plane -> 256 blocks
#define HALO     20                   // 2 cells/step * 10 steps
#define EXPW     76                   // TILE + 2*HALO
#define LSTR     84                   // LDS row stride
#define KSTEP    10
#define NLAUNCH  20
#define NSB      (19*19)              // 361 sub-blocks (4 rows x 4 cols)
#define BLK      512                  // 8 waves/CU

struct MeasIdx { int v[NM]; };
typedef float4 f4;
typedef float2 f2;

// LDS-only barrier (verified R11/R12): skips the vmcnt(0) drain so in-flight
// global (P0/RA) loads span the barrier.
__device__ __forceinline__ void barrier_lds(){
    asm volatile("s_waitcnt lgkmcnt(0)\n\ts_barrier" ::: "memory");
}

// Reassociated stencil (verified R10-R12). 11 VALU ops/point.
__device__ __forceinline__ f4 frow2(f2 L, f4 C, f2 Q,
                                    f4 m2, f4 m1, f4 p1, f4 p2,
                                    f4 O, f4 CFs, f4 RF, f4 D2)
{
    f4 r;
    {
        float s16 = (L.y + C.y) + (m1.x + p1.x);
        float s1  = (L.x + C.z) + (m2.x + p2.x);
        float st  = fmaf(16.f, s16, -s1);
        st = fmaf(-60.f, C.x, st);
        float p = fmaf(2.f, C.x, -O.x);
        p = fmaf(CFs.x, st, p);
        r.x = fmaf(RF.x, D2.x, p);
    }
    {
        float s16 = (C.x + C.z) + (m1.y + p1.y);
        float s1  = (L.y + C.w) + (m2.y + p2.y);
        float st  = fmaf(16.f, s16, -s1);
        st = fmaf(-60.f, C.y, st);
        float p = fmaf(2.f, C.y, -O.y);
        p = fmaf(CFs.y, st, p);
        r.y = fmaf(RF.y, D2.y, p);
    }
    {
        float s16 = (C.y + C.w) + (m1.z + p1.z);
        float s1  = (C.x + Q.x) + (m2.z + p2.z);
        float st  = fmaf(16.f, s16, -s1);
        st = fmaf(-60.f, C.z, st);
        float p = fmaf(2.f, C.z, -O.z);
        p = fmaf(CFs.z, st, p);
        r.z = fmaf(RF.z, D2.z, p);
    }
    {
        float s16 = (C.z + Q.x) + (m1.w + p1.w);
        float s1  = (C.y + Q.y) + (m2.w + p2.w);
        float st  = fmaf(16.f, s16, -s1);
        st = fmaf(-60.f, C.w, st);
        float p = fmaf(2.f, C.w, -O.w);
        p = fmaf(CFs.w, st, p);
        r.w = fmaf(RF.w, D2.w, p);
    }
    return r;
}

__device__ __forceinline__ f4 d2c(f4 c, f4 b, f4 a){
    f4 r;
    r.x = c.x - 2.f*b.x + a.x;
    r.y = c.y - 2.f*b.y + a.y;
    r.z = c.z - 2.f*b.z + a.z;
    r.w = c.w - 2.f*b.w + a.w;
    return r;
}

// Advance KSTEP=10 steps of a 36x36 interior tile of one plane, in LDS.
// 4-row x 4-col sub-blocks: row-neighbor LDS reads (Rm2,Rm1,Rp4,Rp5) amortize
// over 4 rows; interior row neighbors come from register-carried centers.
// LDS pipe traffic per point: 9 cyc vs 12 for the 2-row scheme.
__global__ __launch_bounds__(BLK, 2)
void step_fused(const float* __restrict__ RA, const float* __restrict__ RB,
                float* __restrict__ WA, float* __restrict__ WB,
                const float* __restrict__ P0, const float* __restrict__ x,
                float* __restrict__ out, int J, MeasIdx meas)
{
    __shared__ float lds0[EXPW*LSTR];
    __shared__ float lds1[EXPW*LSTR];
    const int tid = threadIdx.x;
    // XCD-chunk swizzle: all 16 tiles of a plane land on one XCD's L2
    const int sw  = ((blockIdx.x & 7) << 5) | (blockIdx.x >> 3);
    const int pl  = sw >> 4;
    const int t   = sw & 15;
    const int ty  = t >> 2, tx = t & 3;
    const int gy0 = A0 + ty*TILE - HALO;
    const int gx0 = A0 + tx*TILE - HALO;
    const int b   = pl >> 3, rch = pl & 7;
    const size_t pbase = (size_t)pl * PLANE_SZ;
    const f4 z4 = make_float4(0.f,0.f,0.f,0.f);

    // ---- stage ONLY lds1 (stencil source for step 0); zero outside the
    //      active domain or on the first launch. lds0 stays uninitialized
    //      (read only as margin garbage / overwritten at step 0). ----
    {
        const bool zf = (J == 0);
        for (int i = tid; i < EXPW*19; i += BLK){  // 76*19 = 1444 f4 groups
            int ly = i/19, lx4 = (i%19)*4;
            int gyr = gy0 + ly, gxg = gx0 + lx4;
            bool ok = !zf && ((unsigned)(gyr - A0) < 144u)
                          && ((unsigned)(gxg - A0) < 144u);
            f4 vb = z4;
            if (ok) vb = *(const f4*)&RB[pbase + (size_t)gyr*NXg + gxg];
            *(f4*)&lds1[ly*LSTR + lx4] = vb;
        }
    }

    // ---- per-thread sub-block setup (4 rows x 4 cols; 19x19 = 361) ----
    const bool val = (tid < NSB);
    const int gg  = val ? tid : 0;
    const int sbr = gg/19, sbx = gg%19;
    const int ly0 = 4*sbr, lx0 = 4*sbx;
    const int oC  = ly0*LSTR + lx0;
    // valid region at step s: [2s+2, 73-2s]; sub-block intersects iff
    int e1 = (ly0+1) >> 1;                 // ly0+3 >= 2s+2
    int e2 = (73-ly0) >> 1;                // ly0   <= 73-2s
    int e3 = (lx0+1) >> 1;
    int e4 = (73-lx0) >> 1;
    const int sMax = val ? min(min(e1,e2), min(e3,e4)) : -1;
    const int gy = gy0 + ly0, gx = gx0 + lx0;
    // window/active boundaries align to 4-row sub-blocks (gy = 4+36ty+4sbr)
    const bool win = ((unsigned)(gy - WIN0) < (unsigned)CW)
                  && ((unsigned)(gx - WIN0) < (unsigned)CW);
    const int pofs = win ? (gy*NXg + gx) : 0;
    const bool act = ((unsigned)(gy - A0) < 144u) && ((unsigned)(gx - A0) < 144u);

    // ---- O-init directly from RA (verified R12): p_{J-2} center rows ----
    f4 OA0=z4, OA1=z4, OA2=z4, OA3=z4;
    if (val && act && J > 0){
        const float* rp = RA + pbase + (size_t)gy*NXg + gx;
        OA0 = *(const f4*)rp;
        OA1 = *(const f4*)(rp + NXg);
        OA2 = *(const f4*)(rp + 2*NXg);
        OA3 = *(const f4*)(rp + 3*NXg);
    }

    // rf inline (verified R8-R12), 4 rows
    f4 rf0=z4, rf1=z4, rf2=z4, rf3=z4;
    if (win){
        const float* xp = x + (size_t)b*W96SQ + (size_t)(gy-WIN0)*CW + (gx-WIN0);
        f4 xv; float tq;
        xv = *(const f4*)xp;
        tq=1.5f/xv.x; rf0.x=1.f-tq*tq; tq=1.5f/xv.y; rf0.y=1.f-tq*tq;
        tq=1.5f/xv.z; rf0.z=1.f-tq*tq; tq=1.5f/xv.w; rf0.w=1.f-tq*tq;
        xv = *(const f4*)(xp + CW);
        tq=1.5f/xv.x; rf1.x=1.f-tq*tq; tq=1.5f/xv.y; rf1.y=1.f-tq*tq;
        tq=1.5f/xv.z; rf1.z=1.f-tq*tq; tq=1.5f/xv.w; rf1.w=1.f-tq*tq;
        xv = *(const f4*)(xp + 2*CW);
        tq=1.5f/xv.x; rf2.x=1.f-tq*tq; tq=1.5f/xv.y; rf2.y=1.f-tq*tq;
        tq=1.5f/xv.z; rf2.z=1.f-tq*tq; tq=1.5f/xv.w; rf2.w=1.f-tq*tq;
        xv = *(const f4*)(xp + 3*CW);
        tq=1.5f/xv.x; rf3.x=1.f-tq*tq; tq=1.5f/xv.y; rf3.y=1.f-tq*tq;
        tq=1.5f/xv.z; rf3.z=1.f-tq*tq; tq=1.5f/xv.w; rf3.w=1.f-tq*tq;
    }
    // CFs = coef/12, per row
    f4 cf0, cf1, cf2, cf3;
    {
        float v[4][4];
#pragma unroll
        for (int rr=0; rr<4; ++rr){
#pragma unroll
            for (int ii=0; ii<4; ++ii){
                int gxr = gx + ii, gyr = gy + rr;
                bool in = (gxr>=25 && gxr<167 && gyr>=25 && gyr<167);
                float g = 0.3f * (in ? 1.5f : 1e-6f);
                v[rr][ii] = (g*g)*(1.0f/12.0f);
            }
        }
        cf0 = make_float4(v[0][0],v[0][1],v[0][2],v[0][3]);
        cf1 = make_float4(v[1][0],v[1][1],v[1][2],v[1][3]);
        cf2 = make_float4(v[2][0],v[2][1],v[2][2],v[2][3]);
        cf3 = make_float4(v[3][0],v[3][1],v[3][2],v[3][3]);
    }

    // receiver ownership (hoisted)
    bool own = false; int loff = 0; size_t obase = 0;
    if (tid < NM){
        int rv = meas.v[tid];
        int ry = rv / NXg, rx = rv % NXg;
        int dy = ry - (A0 + ty*TILE), dx = rx - (A0 + tx*TILE);
        own = ((unsigned)dy < TILE) && ((unsigned)dx < TILE);
        loff = (dy+HALO)*LSTR + (dx+HALO);
        obase = ((size_t)pl*NM + tid)*NT;
    }

    // ---- P0 register chain (4 rows): Pa=P0[J], Pb=P0[J-1]; D = d2[J] ----
    const float* P0r = P0 + (size_t)rch*NT*PLANE_SZ;
    f4 Pa0=z4,Pa1=z4,Pa2=z4,Pa3=z4, Pb0=z4,Pb1=z4,Pb2=z4,Pb3=z4;
    f4 Dr0=z4,Dr1=z4,Dr2=z4,Dr3=z4;
    if (win){
        const float* p = P0r + (size_t)J*PLANE_SZ + pofs;
        Pa0 = *(const f4*)p;
        Pa1 = *(const f4*)(p + NXg);
        Pa2 = *(const f4*)(p + 2*NXg);
        Pa3 = *(const f4*)(p + 3*NXg);
        if (J >= 1){
            Pb0 = *(const f4*)(p - PLANE_SZ);
            Pb1 = *(const f4*)(p - PLANE_SZ + NXg);
            Pb2 = *(const f4*)(p - PLANE_SZ + 2*NXg);
            Pb3 = *(const f4*)(p - PLANE_SZ + 3*NXg);
        }
        if (J >= 2){
            f4 Pc0 = *(const f4*)(p - 2*PLANE_SZ);
            f4 Pc1 = *(const f4*)(p - 2*PLANE_SZ + NXg);
            f4 Pc2 = *(const f4*)(p - 2*PLANE_SZ + 2*NXg);
            f4 Pc3 = *(const f4*)(p - 2*PLANE_SZ + 3*NXg);
            Dr0 = d2c(Pa0, Pb0, Pc0);
            Dr1 = d2c(Pa1, Pb1, Pc1);
            Dr2 = d2c(Pa2, Pb2, Pc2);
            Dr3 = d2c(Pa3, Pb3, Pc3);
        }
    }

    barrier_lds();

    // center rows of the staged level (lds1), register-carried
    f4 OB0 = *(const f4*)&lds1[oC];
    f4 OB1 = *(const f4*)&lds1[oC+LSTR];
    f4 OB2 = *(const f4*)&lds1[oC+2*LSTR];
    f4 OB3 = *(const f4*)&lds1[oC+3*LSTR];

#pragma unroll
    for (int s=0; s<KSTEP; ++s){
        float* pa = (s&1) ? lds1 : lds0;      // level overwritten with p_{J+s}
        float* pb = (s&1) ? lds0 : lds1;      // stencil source p_{J+s-1}

        // issue next-step P0 loads; they stay in flight across the barrier
        const bool pre = (s+1 < KSTEP) && win && ((s+1) <= sMax);
        f4 Pn0=z4, Pn1=z4, Pn2=z4, Pn3=z4;
        if (pre){
            const float* p = P0r + (size_t)(J+s+1)*PLANE_SZ + pofs;
            Pn0 = *(const f4*)p;
            Pn1 = *(const f4*)(p + NXg);
            Pn2 = *(const f4*)(p + 2*NXg);
            Pn3 = *(const f4*)(p + 3*NXg);
        }

        if (s <= sMax){
            f4 Cr0 = (s&1) ? OA0 : OB0;       // pb center rows (own)
            f4 Cr1 = (s&1) ? OA1 : OB1;
            f4 Cr2 = (s&1) ? OA2 : OB2;
            f4 Cr3 = (s&1) ? OA3 : OB3;
            f4 Oo0 = (s&1) ? OB0 : OA0;       // pa center rows (p_{s-2})
            f4 Oo1 = (s&1) ? OB1 : OA1;
            f4 Oo2 = (s&1) ? OB2 : OA2;
            f4 Oo3 = (s&1) ? OB3 : OA3;
            f4 Rm2 = *(const f4*)&pb[oC - 2*LSTR];
            f4 Rm1 = *(const f4*)&pb[oC -   LSTR];
            f4 Rp4 = *(const f4*)&pb[oC + 4*LSTR];
            f4 Rp5 = *(const f4*)&pb[oC + 5*LSTR];
            f2 L0  = *(const f2*)&pb[oC - 2];
            f2 L1  = *(const f2*)&pb[oC +   LSTR - 2];
            f2 L2  = *(const f2*)&pb[oC + 2*LSTR - 2];
            f2 L3  = *(const f2*)&pb[oC + 3*LSTR - 2];
            f2 Q0  = *(const f2*)&pb[oC + 4];
            f2 Q1  = *(const f2*)&pb[oC +   LSTR + 4];
            f2 Q2  = *(const f2*)&pb[oC + 2*LSTR + 4];
            f2 Q3  = *(const f2*)&pb[oC + 3*LSTR + 4];
            // row r: m2=row r-2, m1=row r-1, p1=row r+1, p2=row r+2
            f4 N0 = frow2(L0, Cr0, Q0, Rm2, Rm1, Cr1, Cr2, Oo0, cf0, rf0, Dr0);
            f4 N1 = frow2(L1, Cr1, Q1, Rm1, Cr0, Cr2, Cr3, Oo1, cf1, rf1, Dr1);
            f4 N2 = frow2(L2, Cr2, Q2, Cr0, Cr1, Cr3, Rp4, Oo2, cf2, rf2, Dr2);
            f4 N3 = frow2(L3, Cr3, Q3, Cr1, Cr2, Rp4, Rp5, Oo3, cf3, rf3, Dr3);
            *(f4*)&pa[oC]          = N0;
            *(f4*)&pa[oC +   LSTR] = N1;
            *(f4*)&pa[oC + 2*LSTR] = N2;
            *(f4*)&pa[oC + 3*LSTR] = N3;
            if (s&1){ OB0=N0; OB1=N1; OB2=N2; OB3=N3; }
            else    { OA0=N0; OA1=N1; OA2=N2; OA3=N3; }
        }

        barrier_lds();

        // roll the d2 chain AFTER the barrier (verified R11/R12)
        if (pre){
            if (J+s+1 >= 2){
                Dr0 = d2c(Pn0, Pa0, Pb0);
                Dr1 = d2c(Pn1, Pa1, Pb1);
                Dr2 = d2c(Pn2, Pa2, Pb2);
                Dr3 = d2c(Pn3, Pa3, Pb3);
            } else { Dr0=z4; Dr1=z4; Dr2=z4; Dr3=z4; }
            Pb0=Pa0; Pb1=Pa1; Pb2=Pa2; Pb3=Pa3;
            Pa0=Pn0; Pa1=Pn1; Pa2=Pn2; Pa3=Pn3;
        }

        if (own) out[obase + (J+s)] = pa[loff];
    }

    // ---- write back interior of the last two levels (skipped on the final
    //      launch: nothing reads the field buffers afterwards) ----
    if (J != (NLAUNCH-1)*KSTEP){
        for (int i = tid; i < TILE*(TILE/4); i += BLK){   // 36*9 = 324 groups
            int r = i/9, c4 = (i%9)*4;
            size_t go = pbase + (size_t)(A0 + ty*TILE + r)*NXg + (A0 + tx*TILE + c4);
            int lo = (r+HALO)*LSTR + (c4+HALO);
            *(f4*)&WB[go] = *(const f4*)&lds1[lo];
            *(f4*)&WA[go] = *(const f4*)&lds0[lo];
        }
    }
}

extern "C" void kernel_launch(void* const* d_in, const int* in_sizes, int n_in,
                              void* d_out, int out_size, void* d_ws, size_t ws_size,
                              hipStream_t stream)
{
    const float* x  = (const float*)d_in[0];   // (2,1,96,96) f32
    const float* P0 = (const float*)d_in[1];   // (1,8,200,192,192) f32
    float* out = (float*)d_out;                // (2,8,32,200) f32

    float* F   = (float*)d_ws;
    float* f0  = F;
    float* f1  = F + (size_t)TOTAL;
    float* f2p = F + 2*(size_t)TOTAL;
    float* f3p = F + 3*(size_t)TOTAL;

    MeasIdx meas;
    for (int k=0;k<NM;++k){
        double th = 2.0*M_PI*(double)k/(double)NM;
        int mx = (int)(96.0 + 70.0*cos(th));
        int my = (int)(96.0 + 70.0*sin(th));
        meas.v[k] = mx*NXg + my;
    }

    float *RA=f0, *RB=f1, *WA=f2p, *WB=f3p;
    for (int L=0; L<NLAUNCH; ++L){
        step_fused<<<256, BLK, 0, stream>>>(RA,RB,WA,WB,P0,x,out,L*KSTEP,meas);
        float* tsw;
        tsw=RA; RA=WA; WA=tsw;
        tsw=RB; RB=WB; WB=tsw;
    }
}

// Round 14
// 223.342 us; speedup vs baseline: 1.2377x; 1.2377x over previous
//
#include <hip/hip_runtime.h>
#include <math.h>

// ---------------- geometry constants ----------------
#define NXg      192
#define PLANE_SZ (NXg*NXg)            // 36864
#define PLANES   16                   // B(2) * NR(8)
#define TOTAL    (PLANES*PLANE_SZ)
#define NT       200
#define NM       32
#define CW       96                   // central window width
#define C0       48                   // central window origin
#define W96SQ    (CW*CW)
#define A0       24                   // active domain [24,168)^2 ; outside ~0 (coef 9e-14)
#define TILE     36                   // interior tile, 16 tiles/plane -> 256 blocks
#define HALO     20                   // 2 cells/step * 10 steps
#define EXPW     76                   // TILE + 2*HALO
#define LSTR     84                   // LDS row stride
#define KSTEP    10
#define NLAUNCH  20
#define NSB      (38*19)              // 722 sub-blocks (2 rows x 4 cols)
#define BLK      768                  // 12 waves/CU

struct MeasIdx { int v[NM]; };
typedef float4 f4;
typedef float2 f2;

// LDS-only barrier (verified R11): skips the vmcnt(0) drain __syncthreads
// would emit, so in-flight global (P0) prefetch loads span the barrier.
// All cross-thread data moves through LDS (lgkmcnt); global loads are
// consumed by the issuing thread via register scoreboard.
__device__ __forceinline__ void barrier_lds(){
    asm volatile("s_waitcnt lgkmcnt(0)\n\ts_barrier" ::: "memory");
}

// Reassociated stencil (verified R10/R11). 11 VALU ops/point.
__device__ __forceinline__ f4 frow2(f2 L, f4 C, f2 Q,
                                    f4 m2, f4 m1, f4 p1, f4 p2,
                                    f4 O, f4 CFs, f4 RF, f4 D2)
{
    f4 r;
    {
        float s16 = (L.y + C.y) + (m1.x + p1.x);
        float s1  = (L.x + C.z) + (m2.x + p2.x);
        float st  = fmaf(16.f, s16, -s1);
        st = fmaf(-60.f, C.x, st);
        float p = fmaf(2.f, C.x, -O.x);
        p = fmaf(CFs.x, st, p);
        r.x = fmaf(RF.x, D2.x, p);
    }
    {
        float s16 = (C.x + C.z) + (m1.y + p1.y);
        float s1  = (L.y + C.w) + (m2.y + p2.y);
        float st  = fmaf(16.f, s16, -s1);
        st = fmaf(-60.f, C.y, st);
        float p = fmaf(2.f, C.y, -O.y);
        p = fmaf(CFs.y, st, p);
        r.y = fmaf(RF.y, D2.y, p);
    }
    {
        float s16 = (C.y + C.w) + (m1.z + p1.z);
        float s1  = (C.x + Q.x) + (m2.z + p2.z);
        float st  = fmaf(16.f, s16, -s1);
        st = fmaf(-60.f, C.z, st);
        float p = fmaf(2.f, C.z, -O.z);
        p = fmaf(CFs.z, st, p);
        r.z = fmaf(RF.z, D2.z, p);
    }
    {
        float s16 = (C.z + Q.x) + (m1.w + p1.w);
        float s1  = (C.y + Q.y) + (m2.w + p2.w);
        float st  = fmaf(16.f, s16, -s1);
        st = fmaf(-60.f, C.w, st);
        float p = fmaf(2.f, C.w, -O.w);
        p = fmaf(CFs.w, st, p);
        r.w = fmaf(RF.w, D2.w, p);
    }
    return r;
}

__device__ __forceinline__ f4 d2c(f4 c, f4 b, f4 a){
    f4 r;
    r.x = c.x - 2.f*b.x + a.x;
    r.y = c.y - 2.f*b.y + a.y;
    r.z = c.z - 2.f*b.z + a.z;
    r.w = c.w - 2.f*b.w + a.w;
    return r;
}

// Advance KSTEP=10 steps of a 36x36 interior tile of one plane, in LDS.
// Structure identical to verified R11; only change: the final launch skips
// the dead field writeback (nothing reads the field buffers afterwards;
// next call's launch 0 stages with zf and never reads them).
__global__ __launch_bounds__(BLK, 3)
void step_fused(const float* __restrict__ RA, const float* __restrict__ RB,
                float* __restrict__ WA, float* __restrict__ WB,
                const float* __restrict__ P0, const float* __restrict__ x,
                float* __restrict__ out, int J, MeasIdx meas)
{
    __shared__ float lds0[EXPW*LSTR];
    __shared__ float lds1[EXPW*LSTR];
    const int tid = threadIdx.x;
    // XCD-chunk swizzle: all 16 tiles of a plane land on one XCD's L2
    const int sw  = ((blockIdx.x & 7) << 5) | (blockIdx.x >> 3);
    const int pl  = sw >> 4;
    const int t   = sw & 15;
    const int ty  = t >> 2, tx = t & 3;
    const int gy0 = A0 + ty*TILE - HALO;
    const int gx0 = A0 + tx*TILE - HALO;
    const int b   = pl >> 3, rch = pl & 7;
    const size_t pbase = (size_t)pl * PLANE_SZ;
    const f4 z4 = make_float4(0.f,0.f,0.f,0.f);

    // ---- load EXPW x EXPW tiles of both levels; zero outside active domain
    //      or on the first launch (initial state is zero) ----
    {
        const bool zf = (J == 0);
        for (int i = tid; i < EXPW*19; i += BLK){  // 76*19 = 1444 f4 groups
            int ly = i/19, lx4 = (i%19)*4;
            int gyr = gy0 + ly, gxg = gx0 + lx4;
            bool ok = !zf && ((unsigned)(gyr - A0) < 144u)
                          && ((unsigned)(gxg - A0) < 144u);
            f4 va = z4, vb = z4;
            if (ok){
                size_t go = pbase + (size_t)gyr*NXg + gxg;
                va = *(const f4*)&RA[go];
                vb = *(const f4*)&RB[go];
            }
            int lo = ly*LSTR + lx4;
            *(f4*)&lds0[lo] = va;
            *(f4*)&lds1[lo] = vb;
        }
    }

    // ---- per-thread sub-block setup ----
    const bool val = (tid < NSB);
    const int gg  = val ? tid : 0;
    const int sby = gg/19, sbx = gg%19;
    const int ly0 = 2*sby, lx0 = 4*sbx;
    const int oC  = ly0*LSTR + lx0;
    int s1 = (ly0-1) >> 1;
    int s2 = (73-ly0) >> 1;
    int s3 = (lx0+1) >> 1;
    int s4 = (73-lx0) >> 1;
    const int sMax = val ? min(min(s1,s2), min(s3,s4)) : -1;
    const int gy = gy0 + ly0, gx = gx0 + lx0;
    const bool win = (gy>=C0 && gy<C0+CW && gx>=C0 && gx<C0+CW);
    const int pofs = win ? (gy*NXg + gx) : 0;

    // rf inline (verified R8-R11)
    f4 rfa, rfb2;
    if (win){
        const float* xp = x + (size_t)b*W96SQ + (size_t)(gy-C0)*CW + (gx-C0);
        f4 x0 = *(const f4*)xp;
        f4 x1 = *(const f4*)(xp + CW);
        float tq;
        tq = 1.5f/x0.x; rfa.x  = 1.0f - tq*tq;
        tq = 1.5f/x0.y; rfa.y  = 1.0f - tq*tq;
        tq = 1.5f/x0.z; rfa.z  = 1.0f - tq*tq;
        tq = 1.5f/x0.w; rfa.w  = 1.0f - tq*tq;
        tq = 1.5f/x1.x; rfb2.x = 1.0f - tq*tq;
        tq = 1.5f/x1.y; rfb2.y = 1.0f - tq*tq;
        tq = 1.5f/x1.z; rfb2.z = 1.0f - tq*tq;
        tq = 1.5f/x1.w; rfb2.w = 1.0f - tq*tq;
    } else {
        rfa = z4; rfb2 = z4;
    }
    // CFs = coef/12, pre-folded for the reassociated stencil
    f4 cfa, cfb;
    {
        float c0v[4], c1v[4];
#pragma unroll
        for (int ii=0; ii<4; ++ii){
            int gxr = gx + ii;
            bool ix = (gxr>=25 && gxr<167);
            float g0 = 0.3f * ((ix && gy  >=25 && gy  <167) ? 1.5f : 1e-6f);
            float g1 = 0.3f * ((ix && gy+1>=25 && gy+1<167) ? 1.5f : 1e-6f);
            c0v[ii] = (g0*g0)*(1.0f/12.0f);
            c1v[ii] = (g1*g1)*(1.0f/12.0f);
        }
        cfa = make_float4(c0v[0],c0v[1],c0v[2],c0v[3]);
        cfb = make_float4(c1v[0],c1v[1],c1v[2],c1v[3]);
    }

    // receiver ownership (hoisted)
    bool own = false; int loff = 0; size_t obase = 0;
    if (tid < NM){
        int rv = meas.v[tid];
        int ry = rv / NXg, rx = rv % NXg;
        int dy = ry - (A0 + ty*TILE), dx = rx - (A0 + tx*TILE);
        own = ((unsigned)dy < TILE) && ((unsigned)dx < TILE);
        loff = (dy+HALO)*LSTR + (dx+HALO);
        obase = ((size_t)pl*NM + tid)*NT;
    }

    // ---- P0 register chain: Pa=P0[J], Pb=P0[J-1]; D = d2 for step 0 ----
    const float* P0r = P0 + (size_t)rch*NT*PLANE_SZ;
    f4 Pa0=z4, Pa1=z4, Pb0=z4, Pb1=z4, D0=z4, D1=z4;
    if (win){
        const float* p = P0r + (size_t)J*PLANE_SZ + pofs;
        Pa0 = *(const f4*)p;
        Pa1 = *(const f4*)(p + NXg);
        if (J >= 1){
            Pb0 = *(const f4*)(p - PLANE_SZ);
            Pb1 = *(const f4*)(p - PLANE_SZ + NXg);
        }
        if (J >= 2){
            f4 Pc0 = *(const f4*)(p - 2*PLANE_SZ);
            f4 Pc1 = *(const f4*)(p - 2*PLANE_SZ + NXg);
            D0 = d2c(Pa0, Pb0, Pc0);
            D1 = d2c(Pa1, Pb1, Pc1);
        }
    }

    barrier_lds();

    // center rows of both levels, register-carried
    f4 OA0 = *(const f4*)&lds0[oC];
    f4 OA1 = *(const f4*)&lds0[oC+LSTR];
    f4 OB0 = *(const f4*)&lds1[oC];
    f4 OB1 = *(const f4*)&lds1[oC+LSTR];

#pragma unroll
    for (int s=0; s<KSTEP; ++s){
        float* pa = (s&1) ? lds1 : lds0;      // level overwritten with p_{J+s}
        float* pb = (s&1) ? lds0 : lds1;      // stencil source p_{J+s-1}

        // issue next-step P0 loads; they stay in flight across the barrier
        const bool pre = (s+1 < KSTEP) && win && ((s+1) <= sMax);
        f4 Pn0 = z4, Pn1 = z4;
        if (pre){
            const float* p = P0r + (size_t)(J+s+1)*PLANE_SZ + pofs;
            Pn0 = *(const f4*)p;
            Pn1 = *(const f4*)(p + NXg);
        }

        if (s <= sMax){
            f4 C0r = (s&1) ? OA0 : OB0;       // pb center rows (own)
            f4 C1r = (s&1) ? OA1 : OB1;
            f4 O0  = (s&1) ? OB0 : OA0;       // pa center rows (p_{s-2})
            f4 O1  = (s&1) ? OB1 : OA1;
            f4 Rm2 = *(const f4*)&pb[oC - 2*LSTR];
            f4 Rm1 = *(const f4*)&pb[oC -   LSTR];
            f4 Rp2 = *(const f4*)&pb[oC + 2*LSTR];
            f4 Rp3 = *(const f4*)&pb[oC + 3*LSTR];
            f2 L0  = *(const f2*)&pb[oC - 2];
            f2 L1  = *(const f2*)&pb[oC + LSTR - 2];
            f2 Q0  = *(const f2*)&pb[oC + 4];
            f2 Q1  = *(const f2*)&pb[oC + LSTR + 4];
            f4 N0 = frow2(L0, C0r, Q0, Rm2, Rm1, C1r, Rp2, O0, cfa, rfa,  D0);
            f4 N1 = frow2(L1, C1r, Q1, Rm1, C0r, Rp2, Rp3, O1, cfb, rfb2, D1);
            *(f4*)&pa[oC]        = N0;
            *(f4*)&pa[oC + LSTR] = N1;
            if (s&1){ OB0=N0; OB1=N1; } else { OA0=N0; OA1=N1; }
        }

        barrier_lds();

        // roll the d2 chain AFTER the barrier (verified R11): the Pn loads
        // had the whole compute phase + barrier to land
        if (pre){
            if (J+s+1 >= 2){
                D0 = d2c(Pn0, Pa0, Pb0);
                D1 = d2c(Pn1, Pa1, Pb1);
            } else { D0 = z4; D1 = z4; }
            Pb0 = Pa0; Pb1 = Pa1;
            Pa0 = Pn0; Pa1 = Pn1;
        }

        if (own) out[obase + (J+s)] = pa[loff];
    }

    // ---- write back interior of the last two levels (skipped on the final
    //      launch: nothing reads the field buffers afterwards) ----
    if (J != (NLAUNCH-1)*KSTEP){
        for (int i = tid; i < TILE*(TILE/4); i += BLK){   // 36*9 = 324 groups
            int r = i/9, c4 = (i%9)*4;
            size_t go = pbase + (size_t)(A0 + ty*TILE + r)*NXg + (A0 + tx*TILE + c4);
            int lo = (r+HALO)*LSTR + (c4+HALO);
            *(f4*)&WB[go] = *(const f4*)&lds1[lo];
            *(f4*)&WA[go] = *(const f4*)&lds0[lo];
        }
    }
}

extern "C" void kernel_launch(void* const* d_in, const int* in_sizes, int n_in,
                              void* d_out, int out_size, void* d_ws, size_t ws_size,
                              hipStream_t stream)
{
    const float* x  = (const float*)d_in[0];   // (2,1,96,96) f32
    const float* P0 = (const float*)d_in[1];   // (1,8,200,192,192) f32
    float* out = (float*)d_out;                // (2,8,32,200) f32

    float* F   = (float*)d_ws;
    float* f0  = F;
    float* f1  = F + (size_t)TOTAL;
    float* f2p = F + 2*(size_t)TOTAL;
    float* f3p = F + 3*(size_t)TOTAL;

    MeasIdx meas;
    for (int k=0;k<NM;++k){
        double th = 2.0*M_PI*(double)k/(double)NM;
        int mx = (int)(96.0 + 70.0*cos(th));
        int my = (int)(96.0 + 70.0*sin(th));
        meas.v[k] = mx*NXg + my;
    }

    float *RA=f0, *RB=f1, *WA=f2p, *WB=f3p;
    for (int L=0; L<NLAUNCH; ++L){
        step_fused<<<256, BLK, 0, stream>>>(RA,RB,WA,WB,P0,x,out,L*KSTEP,meas);
        float* tsw;
        tsw=RA; RA=WA; WA=tsw;
        tsw=RB; RB=WB; WB=tsw;
    }
}